// Round 1
// baseline (17847.740 us; speedup 1.0000x reference)
//
#include <hip/hip_runtime.h>
#include <hip/hip_bf16.h>
#include <math.h>

#define TSEQ 1024
#define CDIM 1024
#define NH   16
#define HD   64
#define NLAYER 12
#define LN_EPS 1e-5f

// ---------------- LayerNorm: one block per row ----------------
__global__ __launch_bounds__(256) void ln_kernel(const float* __restrict__ x,
                                                 const float* __restrict__ g,
                                                 const float* __restrict__ b,
                                                 float* __restrict__ out) {
    int row = blockIdx.x;
    const float* xr = x + row * CDIM;
    float v[4];
    float s = 0.f, ss = 0.f;
#pragma unroll
    for (int i = 0; i < 4; i++) {
        float t = xr[threadIdx.x + i * 256];
        v[i] = t; s += t; ss += t * t;
    }
    __shared__ float r1[256], r2[256];
    r1[threadIdx.x] = s; r2[threadIdx.x] = ss;
    __syncthreads();
    for (int off = 128; off > 0; off >>= 1) {
        if (threadIdx.x < off) {
            r1[threadIdx.x] += r1[threadIdx.x + off];
            r2[threadIdx.x] += r2[threadIdx.x + off];
        }
        __syncthreads();
    }
    float mu  = r1[0] * (1.f / CDIM);
    float var = r2[0] * (1.f / CDIM) - mu * mu;
    float rstd = rsqrtf(var + LN_EPS);
#pragma unroll
    for (int i = 0; i < 4; i++) {
        int c = threadIdx.x + i * 256;
        out[row * CDIM + c] = (v[i] - mu) * rstd * g[c] + b[c];
    }
}

// ---------------- GELU (GPT-2 tanh approximation) ----------------
__device__ __forceinline__ float gelu_f(float x) {
    const float kAlpha = 0.7978845608028654f;  // sqrt(2/pi)
    float x3 = x * x * x;
    return 0.5f * x * (1.f + tanhf(kAlpha * (x + 0.044715f * x3)));
}

// ---------------- fp32 GEMM: out[M,N] = A[M,K] @ W[K,N] + bias (+res, act) ----
// 128x128 tile, BK=8, 256 threads, 8x8 per thread.
template <int ACT>
__global__ __launch_bounds__(256) void gemm_kernel(
    const float* __restrict__ A, const float* __restrict__ W,
    const float* __restrict__ bias, const float* __restrict__ res,
    float* __restrict__ out, int M, int N, int K) {
    __shared__ float As[8][128];
    __shared__ float Bs[8][128];
    int tid = threadIdx.x;
    int m0 = blockIdx.y * 128, n0 = blockIdx.x * 128;
    int aRow = tid >> 1, aCol = (tid & 1) * 4;
    int bRow = tid >> 5, bCol = (tid & 31) * 4;
    int ty = tid >> 4, tx = tid & 15;
    float acc[8][8] = {};

    for (int k0 = 0; k0 < K; k0 += 8) {
        float4 av = *(const float4*)(A + (size_t)(m0 + aRow) * K + k0 + aCol);
        float4 bv = *(const float4*)(W + (size_t)(k0 + bRow) * N + n0 + bCol);
        As[aCol + 0][aRow] = av.x;
        As[aCol + 1][aRow] = av.y;
        As[aCol + 2][aRow] = av.z;
        As[aCol + 3][aRow] = av.w;
        *(float4*)&Bs[bRow][bCol] = bv;
        __syncthreads();
#pragma unroll
        for (int kk = 0; kk < 8; kk++) {
            float a[8], bb[8];
            *(float4*)(a + 0) = *(const float4*)&As[kk][ty * 8 + 0];
            *(float4*)(a + 4) = *(const float4*)&As[kk][ty * 8 + 4];
            *(float4*)(bb + 0) = *(const float4*)&Bs[kk][tx * 8 + 0];
            *(float4*)(bb + 4) = *(const float4*)&Bs[kk][tx * 8 + 4];
#pragma unroll
            for (int i = 0; i < 8; i++)
#pragma unroll
                for (int j = 0; j < 8; j++) acc[i][j] += a[i] * bb[j];
        }
        __syncthreads();
    }

#pragma unroll
    for (int i = 0; i < 8; i++) {
        int m = m0 + ty * 8 + i;
#pragma unroll
        for (int j = 0; j < 8; j++) {
            int n = n0 + tx * 8 + j;
            float v = acc[i][j] + bias[n];
            if (ACT == 1) v = gelu_f(v);
            if (res) v += res[(size_t)m * N + n];
            out[(size_t)m * N + n] = v;
        }
    }
}

// ---------------- Attention: block = (8 query rows, 1 head) ----------------
// qkv: [T, 3C] with q|k|v concatenated; head h occupies cols h*64..h*64+63.
__global__ __launch_bounds__(256) void attn_kernel(
    const float* __restrict__ qkv, const float* __restrict__ mask,
    float* __restrict__ y) {
    int h = blockIdx.y;
    int q0 = blockIdx.x * 8;
    int tid = threadIdx.x;

    __shared__ float qs[8][64];
    __shared__ float ks[64][65];     // padded: kills bank conflicts on ks[kk][d]
    __shared__ float sbuf[8][1024];  // score rows
    __shared__ float rowinv[8];

    // load Q tile
    for (int e = tid; e < 8 * 64; e += 256) {
        int qi = e >> 6, d = e & 63;
        qs[qi][d] = qkv[(size_t)(q0 + qi) * 3072 + h * 64 + d];
    }
    __syncthreads();

    const float scale = 0.125f;  // 1/sqrt(64)
    // Pass A: scores
    for (int kc = 0; kc < 16; kc++) {
        for (int e = tid; e < 64 * 64; e += 256) {
            int r = e >> 6, d = e & 63;
            ks[r][d] = qkv[(size_t)(kc * 64 + r) * 3072 + 1024 + h * 64 + d];
        }
        __syncthreads();
        for (int e = tid; e < 8 * 64; e += 256) {
            int qi = e >> 6, kk = e & 63;
            float dot = 0.f;
#pragma unroll
            for (int d = 0; d < 64; d++) dot += qs[qi][d] * ks[kk][d];
            int kg = kc * 64 + kk;
            sbuf[qi][kg] = dot * scale + (-1e9f) * (1.0f - mask[kg]);
        }
        __syncthreads();
    }

    // Pass B: softmax (8 rows, one 32-lane group per row)
    int g = tid >> 5, lane = tid & 31;
    float mx = -1e30f;
    for (int k = lane; k < 1024; k += 32) mx = fmaxf(mx, sbuf[g][k]);
#pragma unroll
    for (int off = 16; off > 0; off >>= 1) mx = fmaxf(mx, __shfl_xor(mx, off));
    float sum = 0.f;
    for (int k = lane; k < 1024; k += 32) {
        float p = __expf(sbuf[g][k] - mx);
        sbuf[g][k] = p;
        sum += p;
    }
#pragma unroll
    for (int off = 16; off > 0; off >>= 1) sum += __shfl_xor(sum, off);
    if (lane == 0) rowinv[g] = 1.f / sum;
    __syncthreads();

    // Pass C: y = P @ V  (each thread: 2 outputs, (qi, d) and (qi+4, d))
    float acc0 = 0.f, acc1 = 0.f;
    int d = tid & 63;
    int qiA = tid >> 6;  // 0..3
    for (int kc = 0; kc < 16; kc++) {
        __syncthreads();  // previous chunk fully consumed before overwrite
        for (int e = tid; e < 64 * 64; e += 256) {
            int r = e >> 6, dd = e & 63;
            ks[r][dd] = qkv[(size_t)(kc * 64 + r) * 3072 + 2048 + h * 64 + dd];
        }
        __syncthreads();
#pragma unroll
        for (int kk = 0; kk < 64; kk++) {
            float vv = ks[kk][d];
            acc0 += sbuf[qiA][kc * 64 + kk] * vv;
            acc1 += sbuf[qiA + 4][kc * 64 + kk] * vv;
        }
    }
    y[(size_t)(q0 + qiA) * 1024 + h * 64 + d] = acc0 * rowinv[qiA];
    y[(size_t)(q0 + qiA + 4) * 1024 + h * 64 + d] = acc1 * rowinv[qiA + 4];
}

// ---------------- launch ----------------
extern "C" void kernel_launch(void* const* d_in, const int* in_sizes, int n_in,
                              void* d_out, int out_size, void* d_ws, size_t ws_size,
                              hipStream_t stream) {
    const float* inputs_embeds = (const float*)d_in[0];
    const float* attn_mask     = (const float*)d_in[1];
    const float* ln1_g = (const float*)d_in[2];
    const float* ln1_b = (const float*)d_in[3];
    const float* Wqkv  = (const float*)d_in[4];
    const float* bqkv  = (const float*)d_in[5];
    const float* Wo    = (const float*)d_in[6];
    const float* bo    = (const float*)d_in[7];
    const float* ln2_g = (const float*)d_in[8];
    const float* ln2_b = (const float*)d_in[9];
    const float* Wfc   = (const float*)d_in[10];
    const float* bfc   = (const float*)d_in[11];
    const float* Wmp   = (const float*)d_in[12];
    const float* bmp   = (const float*)d_in[13];
    const float* lnf_g = (const float*)d_in[14];
    const float* lnf_b = (const float*)d_in[15];
    float* out = (float*)d_out;

    float* ws = (float*)d_ws;
    float* x     = ws;                     // 1M floats
    float* hbuf  = ws + (1 << 20);         // 1M
    float* qkv   = ws + (2 << 20);         // 3M
    float* ybuf  = ws + (5 << 20);         // 1M
    float* fcbuf = ws + (6 << 20);         // 4M

    hipMemcpyAsync(x, inputs_embeds, (size_t)(1 << 20) * sizeof(float),
                   hipMemcpyDeviceToDevice, stream);

    for (int l = 0; l < NLAYER; l++) {
        ln_kernel<<<TSEQ, 256, 0, stream>>>(x, ln1_g + l * CDIM, ln1_b + l * CDIM, hbuf);
        gemm_kernel<0><<<dim3(24, 8), 256, 0, stream>>>(
            hbuf, Wqkv + (size_t)l * CDIM * 3 * CDIM, bqkv + (size_t)l * 3 * CDIM,
            nullptr, qkv, 1024, 3072, 1024);
        attn_kernel<<<dim3(128, 16), 256, 0, stream>>>(qkv, attn_mask, ybuf);
        gemm_kernel<0><<<dim3(8, 8), 256, 0, stream>>>(
            ybuf, Wo + (size_t)l * CDIM * CDIM, bo + (size_t)l * CDIM,
            x, x, 1024, 1024, 1024);
        ln_kernel<<<TSEQ, 256, 0, stream>>>(x, ln2_g + l * CDIM, ln2_b + l * CDIM, hbuf);
        gemm_kernel<1><<<dim3(32, 8), 256, 0, stream>>>(
            hbuf, Wfc + (size_t)l * CDIM * 4 * CDIM, bfc + (size_t)l * 4 * CDIM,
            nullptr, fcbuf, 1024, 4096, 1024);
        gemm_kernel<0><<<dim3(8, 8), 256, 0, stream>>>(
            fcbuf, Wmp + (size_t)l * 4 * CDIM * CDIM, bmp + (size_t)l * CDIM,
            x, x, 1024, 1024, 4096);
    }
    ln_kernel<<<TSEQ, 256, 0, stream>>>(x, lnf_g, lnf_b, out);
}

// Round 4
// 2756.630 us; speedup vs baseline: 6.4745x; 6.4745x over previous
//
#include <hip/hip_runtime.h>
#include <hip/hip_bf16.h>
#include <math.h>

#define LN_EPS 1e-5f

typedef unsigned short u16;
typedef __attribute__((ext_vector_type(8))) _Float16 f16x8;
typedef __attribute__((ext_vector_type(4))) float f32x4;

__device__ __forceinline__ u16 f2h(float x) {
    _Float16 h = (_Float16)x;
    return __builtin_bit_cast(u16, h);
}
__device__ __forceinline__ void stv(float* p, float v) { *p = v; }
__device__ __forceinline__ void stv(u16* p, float v) { *p = f2h(v); }

__device__ __forceinline__ float gelu_f(float x) {
    const float kA = 0.7978845608028654f;  // sqrt(2/pi)
    return 0.5f * x * (1.f + tanhf(kA * (x + 0.044715f * x * x * x)));
}

// ---------------- LayerNorm: one block per row, templated output ----------------
template <typename OT>
__global__ __launch_bounds__(256) void ln_kernel(const float* __restrict__ x,
                                                 const float* __restrict__ gam,
                                                 const float* __restrict__ bet,
                                                 OT* __restrict__ out) {
    int row = blockIdx.x;
    const float* xr = x + (size_t)row * 1024;
    float v[4];
    float s = 0.f, ss = 0.f;
#pragma unroll
    for (int i = 0; i < 4; i++) {
        float t = xr[threadIdx.x + i * 256];
        v[i] = t; s += t; ss += t * t;
    }
    __shared__ float r1[256], r2[256];
    r1[threadIdx.x] = s; r2[threadIdx.x] = ss;
    __syncthreads();
    for (int off = 128; off > 0; off >>= 1) {
        if (threadIdx.x < off) {
            r1[threadIdx.x] += r1[threadIdx.x + off];
            r2[threadIdx.x] += r2[threadIdx.x + off];
        }
        __syncthreads();
    }
    float mu = r1[0] * (1.f / 1024.f);
    float var = r2[0] * (1.f / 1024.f) - mu * mu;
    float rstd = rsqrtf(var + LN_EPS);
#pragma unroll
    for (int i = 0; i < 4; i++) {
        int c = threadIdx.x + i * 256;
        stv(&out[(size_t)row * 1024 + c], (v[i] - mu) * rstd * gam[c] + bet[c]);
    }
}

// ---------------- weight fp32 [K][N] -> fp16 [N][K] transpose-convert ----------------
__global__ __launch_bounds__(256) void tr_cvt(const float* __restrict__ W,
                                              u16* __restrict__ Wt, int K, int N) {
    __shared__ float tile[64][65];
    int k0 = blockIdx.y * 64, n0 = blockIdx.x * 64;
    int t = threadIdx.x;
    int r = t >> 4, c4 = (t & 15) * 4;
#pragma unroll
    for (int p = 0; p < 4; p++) {
        float4 v = *(const float4*)(W + (size_t)(k0 + p * 16 + r) * N + n0 + c4);
        tile[p * 16 + r][c4 + 0] = v.x;
        tile[p * 16 + r][c4 + 1] = v.y;
        tile[p * 16 + r][c4 + 2] = v.z;
        tile[p * 16 + r][c4 + 3] = v.w;
    }
    __syncthreads();
#pragma unroll
    for (int p = 0; p < 4; p++) {
        int n = p * 16 + r;
        ushort4 o;
        o.x = f2h(tile[c4 + 0][n]);
        o.y = f2h(tile[c4 + 1][n]);
        o.z = f2h(tile[c4 + 2][n]);
        o.w = f2h(tile[c4 + 3][n]);
        *(ushort4*)(Wt + (size_t)(n0 + n) * K + k0 + c4) = o;
    }
}

// ---------------- u16 transpose: V [1024 key][stride 3072] -> vT [1024 d][1024 key] ----
__global__ __launch_bounds__(256) void tr16(const u16* __restrict__ in,
                                            u16* __restrict__ outp) {
    __shared__ u16 tile[64][65];
    int k0 = blockIdx.y * 64, c0 = blockIdx.x * 64;
    int t = threadIdx.x;
    int r = t >> 4, c4 = (t & 15) * 4;
#pragma unroll
    for (int p = 0; p < 4; p++) {
        ushort4 v = *(const ushort4*)(in + (size_t)(k0 + p * 16 + r) * 3072 + c0 + c4);
        tile[p * 16 + r][c4 + 0] = v.x;
        tile[p * 16 + r][c4 + 1] = v.y;
        tile[p * 16 + r][c4 + 2] = v.z;
        tile[p * 16 + r][c4 + 3] = v.w;
    }
    __syncthreads();
#pragma unroll
    for (int p = 0; p < 4; p++) {
        int c = p * 16 + r;
        ushort4 o;
        o.x = tile[c4 + 0][c];
        o.y = tile[c4 + 1][c];
        o.z = tile[c4 + 2][c];
        o.w = tile[c4 + 3][c];
        *(ushort4*)(outp + (size_t)(c0 + c) * 1024 + k0 + c4) = o;
    }
}

// ---------------- fp16 MFMA GEMM: out[M,N] = A[M,K] @ Bt[N,K]^T + bias ----------------
// 128x128 tile, BK=64, 4 waves (2x2), per-wave 64x64 = 4x4 MFMA frags.
// LDS layout [128 rows][8 slots of 8 u16], slot XOR-swizzled by (row&7).
template <int ACT, int RES, typename OT>
__global__ __launch_bounds__(256, 2) void gemm_f16(
    const u16* __restrict__ A, const u16* __restrict__ Bt,
    const float* __restrict__ bias, const float* __restrict__ res,
    OT* __restrict__ out, int M, int N, int K) {
    __shared__ u16 As[128 * 64];
    __shared__ u16 Bs[128 * 64];
    int tid = threadIdx.x;
    int w = tid >> 6, l = tid & 63;
    int wm = w >> 1, wn = w & 1;
    int lr = l & 15, g = l >> 4;
    int m0 = blockIdx.y * 128, n0 = blockIdx.x * 128;

    f32x4 acc[4][4] = {};

    for (int k0 = 0; k0 < K; k0 += 64) {
        __syncthreads();
#pragma unroll
        for (int i = 0; i < 4; i++) {
            int chunk = i * 256 + tid;           // 1024 chunks of 8 u16
            int row = chunk >> 3, slot = chunk & 7;
            int ps = ((slot ^ (row & 7)) * 8);
            f16x8 va = *(const f16x8*)(A + (size_t)(m0 + row) * K + k0 + slot * 8);
            *(f16x8*)(As + row * 64 + ps) = va;
            f16x8 vb = *(const f16x8*)(Bt + (size_t)(n0 + row) * K + k0 + slot * 8);
            *(f16x8*)(Bs + row * 64 + ps) = vb;
        }
        __syncthreads();

        f16x8 af[4][2], bfrag[4][2];
#pragma unroll
        for (int m = 0; m < 4; m++)
#pragma unroll
            for (int kf = 0; kf < 2; kf++) {
                int row = wm * 64 + m * 16 + lr;
                af[m][kf] = *(const f16x8*)(As + row * 64 + (((kf * 4 + g) ^ (row & 7)) * 8));
            }
#pragma unroll
        for (int n = 0; n < 4; n++)
#pragma unroll
            for (int kf = 0; kf < 2; kf++) {
                int row = wn * 64 + n * 16 + lr;
                bfrag[n][kf] = *(const f16x8*)(Bs + row * 64 + (((kf * 4 + g) ^ (row & 7)) * 8));
            }
#pragma unroll
        for (int kf = 0; kf < 2; kf++)
#pragma unroll
            for (int m = 0; m < 4; m++)
#pragma unroll
                for (int n = 0; n < 4; n++)
                    acc[m][n] = __builtin_amdgcn_mfma_f32_16x16x32_f16(
                        af[m][kf], bfrag[n][kf], acc[m][n], 0, 0, 0);
    }

#pragma unroll
    for (int m = 0; m < 4; m++) {
#pragma unroll
        for (int n = 0; n < 4; n++) {
            int col = n0 + wn * 64 + n * 16 + lr;
            float bv = bias[col];
#pragma unroll
            for (int r = 0; r < 4; r++) {
                int row = m0 + wm * 64 + m * 16 + 4 * g + r;
                float v = acc[m][n][r] + bv;
                if (ACT) v = gelu_f(v);
                if (RES) v += res[(size_t)row * N + col];
                stv(&out[(size_t)row * N + col], v);
            }
        }
    }
}

// ---------------- flash MFMA attention (no tr-reads) ----------------
// block = (64 q rows, 1 head); 4 waves, wave owns 16 q rows.
// qkv fp16 [1024][3072] (q|k|v); vT fp16 [1024 d-cols][1024 keys].
// K in LDS [key][d] slot-swizzled; V in LDS [d][key] slot-swizzled (from vT);
// P in per-wave LDS [q][key] slot-swizzled. All fragment reads = ds_read_b128
// with the same verified GEMM pattern.
__global__ __launch_bounds__(256, 2) void attn_mfma(
    const u16* __restrict__ qkv, const u16* __restrict__ vT,
    const float* __restrict__ mask, u16* __restrict__ y) {
    int h = blockIdx.y;
    int q0 = blockIdx.x * 64;
    int tid = threadIdx.x;
    int w = tid >> 6, l = tid & 63;
    int lr = l & 15, g = l >> 4;

    __shared__ u16 Ks[64 * 64];      // [key][d], slot-XOR swizzled
    __shared__ u16 Vs[64 * 64];      // [d][key], slot-XOR swizzled
    __shared__ u16 Ps[4 * 16 * 64];  // per-wave P: [q][key], slot-XOR swizzled
    __shared__ float maskb[1024];

    for (int i = tid; i < 1024; i += 256) maskb[i] = -1e9f * (1.f - mask[i]);

    f16x8 qf[2];
#pragma unroll
    for (int kf = 0; kf < 2; kf++)
        qf[kf] = *(const f16x8*)(qkv + (size_t)(q0 + w * 16 + lr) * 3072 + h * 64 + kf * 32 + g * 8);

    f32x4 o[4] = {};
    float mrow[4], lrow[4];
#pragma unroll
    for (int r = 0; r < 4; r++) { mrow[r] = -1e30f; lrow[r] = 0.f; }

    u16* Psw = Ps + w * 1024;

    for (int kc = 0; kc < 16; kc++) {
        __syncthreads();
#pragma unroll
        for (int i = 0; i < 2; i++) {
            int chunk = i * 256 + tid;      // 512 chunks of 8 u16 each
            int row = chunk >> 3, slot = chunk & 7;
            int ps = ((slot ^ (row & 7)) * 8);
            // K tile: rows = keys, cols = d
            f16x8 kv = *(const f16x8*)(qkv + (size_t)(kc * 64 + row) * 3072 + 1024 + h * 64 + slot * 8);
            *(f16x8*)(Ks + row * 64 + ps) = kv;
            // V tile from vT: rows = d, cols = keys
            f16x8 vv = *(const f16x8*)(vT + (size_t)(h * 64 + row) * 1024 + kc * 64 + slot * 8);
            *(f16x8*)(Vs + row * 64 + ps) = vv;
        }
        __syncthreads();

        // S = Q @ K^T  (rows 4g+r, cols lr within each 16-key frag)
        f32x4 s[4] = {};
#pragma unroll
        for (int n = 0; n < 4; n++)
#pragma unroll
            for (int kf = 0; kf < 2; kf++) {
                int row = n * 16 + lr;
                f16x8 kfrag = *(const f16x8*)(Ks + row * 64 + (((kf * 4 + g) ^ (row & 7)) * 8));
                s[n] = __builtin_amdgcn_mfma_f32_16x16x32_f16(qf[kf], kfrag, s[n], 0, 0, 0);
            }

        // online softmax (per r: row 4g+r; reduce over 4 n-frags + 16 lanes)
        float scl[4], mnew[4], psum[4];
#pragma unroll
        for (int r = 0; r < 4; r++) {
            float mx = -1e30f;
#pragma unroll
            for (int n = 0; n < 4; n++) {
                float sv = s[n][r] * 0.125f + maskb[kc * 64 + n * 16 + lr];
                s[n][r] = sv;
                mx = fmaxf(mx, sv);
            }
            mx = fmaxf(mx, __shfl_xor(mx, 1));
            mx = fmaxf(mx, __shfl_xor(mx, 2));
            mx = fmaxf(mx, __shfl_xor(mx, 4));
            mx = fmaxf(mx, __shfl_xor(mx, 8));
            mnew[r] = fmaxf(mrow[r], mx);
            scl[r] = __expf(mrow[r] - mnew[r]);
            mrow[r] = mnew[r];
            psum[r] = 0.f;
        }
        // P = exp(S - m); write P to per-wave LDS [q][key] (slot-swizzled)
#pragma unroll
        for (int n = 0; n < 4; n++) {
            float p0 = __expf(s[n][0] - mnew[0]);
            float p1 = __expf(s[n][1] - mnew[1]);
            float p2 = __expf(s[n][2] - mnew[2]);
            float p3 = __expf(s[n][3] - mnew[3]);
            psum[0] += p0; psum[1] += p1; psum[2] += p2; psum[3] += p3;
            int col = n * 16 + lr, cs = col >> 3, cl = col & 7;
            int r0 = 4 * g;
            Psw[(r0 + 0) * 64 + ((cs ^ ((r0 + 0) & 7)) * 8) + cl] = f2h(p0);
            Psw[(r0 + 1) * 64 + ((cs ^ ((r0 + 1) & 7)) * 8) + cl] = f2h(p1);
            Psw[(r0 + 2) * 64 + ((cs ^ ((r0 + 2) & 7)) * 8) + cl] = f2h(p2);
            Psw[(r0 + 3) * 64 + ((cs ^ ((r0 + 3) & 7)) * 8) + cl] = f2h(p3);
        }
#pragma unroll
        for (int r = 0; r < 4; r++) {
            float ps_ = psum[r];
            ps_ += __shfl_xor(ps_, 1);
            ps_ += __shfl_xor(ps_, 2);
            ps_ += __shfl_xor(ps_, 4);
            ps_ += __shfl_xor(ps_, 8);
            lrow[r] = lrow[r] * scl[r] + ps_;
#pragma unroll
            for (int dn = 0; dn < 4; dn++) o[dn][r] *= scl[r];
        }

        // PV: A = P (row=q=lr, k=keys), B = V (row=d, k=keys). Same-wave LDS
        // RAW on Ps is in-order; Vs guarded by the staging barrier above.
        f16x8 pa[2];
#pragma unroll
        for (int kf = 0; kf < 2; kf++)
            pa[kf] = *(const f16x8*)(Psw + lr * 64 + (((kf * 4 + g) ^ (lr & 7)) * 8));
#pragma unroll
        for (int dn = 0; dn < 4; dn++) {
#pragma unroll
            for (int kf = 0; kf < 2; kf++) {
                int row = dn * 16 + lr;
                f16x8 vb = *(const f16x8*)(Vs + row * 64 + (((kf * 4 + g) ^ (row & 7)) * 8));
                o[dn] = __builtin_amdgcn_mfma_f32_16x16x32_f16(pa[kf], vb, o[dn], 0, 0, 0);
            }
        }
    }

    float inv[4];
#pragma unroll
    for (int r = 0; r < 4; r++) inv[r] = 1.f / lrow[r];
#pragma unroll
    for (int dn = 0; dn < 4; dn++)
#pragma unroll
        for (int r = 0; r < 4; r++) {
            int row = q0 + w * 16 + 4 * g + r;
            int col = h * 64 + dn * 16 + lr;
            y[(size_t)row * 1024 + col] = f2h(o[dn][r] * inv[r]);
        }
}

// ---------------- launch ----------------
extern "C" void kernel_launch(void* const* d_in, const int* in_sizes, int n_in,
                              void* d_out, int out_size, void* d_ws, size_t ws_size,
                              hipStream_t stream) {
    const float* inputs_embeds = (const float*)d_in[0];
    const float* attn_mask     = (const float*)d_in[1];
    const float* ln1_g = (const float*)d_in[2];
    const float* ln1_b = (const float*)d_in[3];
    const float* Wqkv  = (const float*)d_in[4];
    const float* bqkv  = (const float*)d_in[5];
    const float* Wo    = (const float*)d_in[6];
    const float* bo    = (const float*)d_in[7];
    const float* ln2_g = (const float*)d_in[8];
    const float* ln2_b = (const float*)d_in[9];
    const float* Wfc   = (const float*)d_in[10];
    const float* bfc   = (const float*)d_in[11];
    const float* Wmp   = (const float*)d_in[12];
    const float* bmp   = (const float*)d_in[13];
    const float* lnf_g = (const float*)d_in[14];
    const float* lnf_b = (const float*)d_in[15];
    float* out = (float*)d_out;

    char* ws = (char*)d_ws;
    float* x   = (float*)ws;                              // 4 MB fp32 residual
    u16* hbuf  = (u16*)(ws + (4u << 20));                 // 2 MB fp16 (ln out / attn y)
    u16* qkvb  = (u16*)(ws + (6u << 20));                 // 8 MB region (qkv 6MB | fc 8MB)
    u16* fcb   = qkvb;
    u16* ybuf  = hbuf;
    u16* wqT   = (u16*)(ws + (14u << 20));                // 6 MB  [3072][1024]
    u16* woT   = (u16*)(ws + (20u << 20));                // 2 MB  [1024][1024]
    u16* wfT   = (u16*)(ws + (22u << 20));                // 8 MB  [4096][1024]
    u16* wmT   = (u16*)(ws + (30u << 20));                // 8 MB  [1024][4096]
    u16* vTb   = (u16*)(ws + (38u << 20));                // 2 MB  [1024][1024] -> 40 MB total

    hipMemcpyAsync(x, inputs_embeds, (size_t)(1 << 20) * sizeof(float),
                   hipMemcpyDeviceToDevice, stream);

    for (int l = 0; l < 12; l++) {
        tr_cvt<<<dim3(48, 16), 256, 0, stream>>>(Wqkv + (size_t)l * 1024 * 3072, wqT, 1024, 3072);
        tr_cvt<<<dim3(16, 16), 256, 0, stream>>>(Wo + (size_t)l * 1024 * 1024, woT, 1024, 1024);
        tr_cvt<<<dim3(64, 16), 256, 0, stream>>>(Wfc + (size_t)l * 1024 * 4096, wfT, 1024, 4096);
        tr_cvt<<<dim3(16, 64), 256, 0, stream>>>(Wmp + (size_t)l * 4096 * 1024, wmT, 4096, 1024);

        ln_kernel<u16><<<1024, 256, 0, stream>>>(x, ln1_g + l * 1024, ln1_b + l * 1024, hbuf);
        gemm_f16<0, 0, u16><<<dim3(24, 8), 256, 0, stream>>>(
            hbuf, wqT, bqkv + (size_t)l * 3072, nullptr, qkvb, 1024, 3072, 1024);
        tr16<<<dim3(16, 16), 256, 0, stream>>>(qkvb + 2048, vTb);
        attn_mfma<<<dim3(16, 16), 256, 0, stream>>>(qkvb, vTb, attn_mask, ybuf);
        gemm_f16<0, 1, float><<<dim3(8, 8), 256, 0, stream>>>(
            ybuf, woT, bo + (size_t)l * 1024, x, x, 1024, 1024, 1024);
        ln_kernel<u16><<<1024, 256, 0, stream>>>(x, ln2_g + l * 1024, ln2_b + l * 1024, hbuf);
        gemm_f16<1, 0, u16><<<dim3(32, 8), 256, 0, stream>>>(
            hbuf, wfT, bfc + (size_t)l * 4096, nullptr, fcb, 1024, 4096, 1024);
        gemm_f16<0, 1, float><<<dim3(8, 8), 256, 0, stream>>>(
            fcb, wmT, bmp + (size_t)l * 1024, x, x, 1024, 1024, 4096);
    }
    ln_kernel<float><<<1024, 256, 0, stream>>>(x, lnf_g, lnf_b, out);
}

// Round 5
// 1972.469 us; speedup vs baseline: 9.0484x; 1.3976x over previous
//
#include <hip/hip_runtime.h>
#include <hip/hip_bf16.h>
#include <math.h>

#define LN_EPS 1e-5f

typedef unsigned short u16;
typedef __attribute__((ext_vector_type(8))) _Float16 f16x8;
typedef __attribute__((ext_vector_type(4))) float f32x4;

__device__ __forceinline__ u16 f2h(float x) {
    _Float16 h = (_Float16)x;
    return __builtin_bit_cast(u16, h);
}
__device__ __forceinline__ void stv(float* p, float v) { *p = v; }
__device__ __forceinline__ void stv(u16* p, float v) { *p = f2h(v); }

__device__ __forceinline__ float gelu_f(float x) {
    const float kA = 0.7978845608028654f;  // sqrt(2/pi)
    return 0.5f * x * (1.f + tanhf(kA * (x + 0.044715f * x * x * x)));
}

// async global->LDS, 16B per lane; LDS dest = wave-uniform base + lane*16
__device__ __forceinline__ void gl_lds16(const u16* g, u16* l) {
    __builtin_amdgcn_global_load_lds(
        (const __attribute__((address_space(1))) unsigned int*)g,
        (__attribute__((address_space(3))) unsigned int*)l, 16, 0, 0);
}

// ---------------- LayerNorm: one block per row, templated output ----------------
template <typename OT>
__global__ __launch_bounds__(256) void ln_kernel(const float* __restrict__ x,
                                                 const float* __restrict__ gam,
                                                 const float* __restrict__ bet,
                                                 OT* __restrict__ out) {
    int row = blockIdx.x;
    const float* xr = x + (size_t)row * 1024;
    float v[4];
    float s = 0.f, ss = 0.f;
#pragma unroll
    for (int i = 0; i < 4; i++) {
        float t = xr[threadIdx.x + i * 256];
        v[i] = t; s += t; ss += t * t;
    }
    __shared__ float r1[256], r2[256];
    r1[threadIdx.x] = s; r2[threadIdx.x] = ss;
    __syncthreads();
    for (int off = 128; off > 0; off >>= 1) {
        if (threadIdx.x < off) {
            r1[threadIdx.x] += r1[threadIdx.x + off];
            r2[threadIdx.x] += r2[threadIdx.x + off];
        }
        __syncthreads();
    }
    float mu = r1[0] * (1.f / 1024.f);
    float var = r2[0] * (1.f / 1024.f) - mu * mu;
    float rstd = rsqrtf(var + LN_EPS);
#pragma unroll
    for (int i = 0; i < 4; i++) {
        int c = threadIdx.x + i * 256;
        stv(&out[(size_t)row * 1024 + c], (v[i] - mu) * rstd * gam[c] + bet[c]);
    }
}

// ---------------- weight fp32 [K][N] -> fp16 [N][K] transpose-convert ----------------
__global__ __launch_bounds__(256) void tr_cvt(const float* __restrict__ W,
                                              u16* __restrict__ Wt, int K, int N) {
    __shared__ float tile[64][65];
    int k0 = blockIdx.y * 64, n0 = blockIdx.x * 64;
    int t = threadIdx.x;
    int r = t >> 4, c4 = (t & 15) * 4;
#pragma unroll
    for (int p = 0; p < 4; p++) {
        float4 v = *(const float4*)(W + (size_t)(k0 + p * 16 + r) * N + n0 + c4);
        tile[p * 16 + r][c4 + 0] = v.x;
        tile[p * 16 + r][c4 + 1] = v.y;
        tile[p * 16 + r][c4 + 2] = v.z;
        tile[p * 16 + r][c4 + 3] = v.w;
    }
    __syncthreads();
#pragma unroll
    for (int p = 0; p < 4; p++) {
        int n = p * 16 + r;
        ushort4 o;
        o.x = f2h(tile[c4 + 0][n]);
        o.y = f2h(tile[c4 + 1][n]);
        o.z = f2h(tile[c4 + 2][n]);
        o.w = f2h(tile[c4 + 3][n]);
        *(ushort4*)(Wt + (size_t)(n0 + n) * K + k0 + c4) = o;
    }
}

// ---------------- u16 transpose: V [1024 key][stride 3072] -> vT [1024 d][1024 key] ----
__global__ __launch_bounds__(256) void tr16(const u16* __restrict__ in,
                                            u16* __restrict__ outp) {
    __shared__ u16 tile[64][65];
    int k0 = blockIdx.y * 64, c0 = blockIdx.x * 64;
    int t = threadIdx.x;
    int r = t >> 4, c4 = (t & 15) * 4;
#pragma unroll
    for (int p = 0; p < 4; p++) {
        ushort4 v = *(const ushort4*)(in + (size_t)(k0 + p * 16 + r) * 3072 + c0 + c4);
        tile[p * 16 + r][c4 + 0] = v.x;
        tile[p * 16 + r][c4 + 1] = v.y;
        tile[p * 16 + r][c4 + 2] = v.z;
        tile[p * 16 + r][c4 + 3] = v.w;
    }
    __syncthreads();
#pragma unroll
    for (int p = 0; p < 4; p++) {
        int c = p * 16 + r;
        ushort4 o;
        o.x = tile[c4 + 0][c];
        o.y = tile[c4 + 1][c];
        o.z = tile[c4 + 2][c];
        o.w = tile[c4 + 3][c];
        *(ushort4*)(outp + (size_t)(c0 + c) * 1024 + k0 + c4) = o;
    }
}

// ---------------- fp16 MFMA GEMM: out[M,N] = A[M,K] @ Bt[N,K]^T + bias ----------------
// BMxBN tile, BK=64, 4 waves (2x2), per-wave (BM/2)x(BN/2).
// LDS: linear dest for global_load_lds; k-slot swizzle applied on the GLOBAL
// source (slot' = slot ^ (row&7)), so LDS slot s of row r holds k-chunk
// s^(r&7); ds_read_b128 fragment reads use the original verified pattern.
template <int BM, int BN, int ACT, int RES, typename OT>
__global__ __launch_bounds__(256) void gemm_f16(
    const u16* __restrict__ A, const u16* __restrict__ Bt,
    const float* __restrict__ bias, const float* __restrict__ res,
    OT* __restrict__ out, int M, int N, int K) {
    __shared__ u16 As[BM * 64];
    __shared__ u16 Bs[BN * 64];
    constexpr int WM = BM / 2, WN = BN / 2;
    constexpr int FM = WM / 16, FN = WN / 16;
    constexpr int ACH = BM * 64 / 8 / 256;
    constexpr int BCH = BN * 64 / 8 / 256;
    int tid = threadIdx.x;
    int w = tid >> 6, l = tid & 63;
    int wm = w >> 1, wn = w & 1;
    int lr = l & 15, g = l >> 4;
    int m0 = blockIdx.y * BM, n0 = blockIdx.x * BN;

    f32x4 acc[FM][FN] = {};

    for (int k0 = 0; k0 < K; k0 += 64) {
        __syncthreads();
#pragma unroll
        for (int i = 0; i < ACH; i++) {
            int chunk = i * 256 + tid;
            int row = chunk >> 3, s = chunk & 7, sg = s ^ (row & 7);
            gl_lds16(A + (size_t)(m0 + row) * K + k0 + sg * 8, As + chunk * 8);
        }
#pragma unroll
        for (int i = 0; i < BCH; i++) {
            int chunk = i * 256 + tid;
            int row = chunk >> 3, s = chunk & 7, sg = s ^ (row & 7);
            gl_lds16(Bt + (size_t)(n0 + row) * K + k0 + sg * 8, Bs + chunk * 8);
        }
        __syncthreads();

        f16x8 af[FM][2], bfrag[FN][2];
#pragma unroll
        for (int m = 0; m < FM; m++)
#pragma unroll
            for (int kf = 0; kf < 2; kf++) {
                int row = wm * WM + m * 16 + lr;
                af[m][kf] = *(const f16x8*)(As + row * 64 + (((kf * 4 + g) ^ (row & 7)) * 8));
            }
#pragma unroll
        for (int n = 0; n < FN; n++)
#pragma unroll
            for (int kf = 0; kf < 2; kf++) {
                int row = wn * WN + n * 16 + lr;
                bfrag[n][kf] = *(const f16x8*)(Bs + row * 64 + (((kf * 4 + g) ^ (row & 7)) * 8));
            }
#pragma unroll
        for (int kf = 0; kf < 2; kf++)
#pragma unroll
            for (int m = 0; m < FM; m++)
#pragma unroll
                for (int n = 0; n < FN; n++)
                    acc[m][n] = __builtin_amdgcn_mfma_f32_16x16x32_f16(
                        af[m][kf], bfrag[n][kf], acc[m][n], 0, 0, 0);
    }

#pragma unroll
    for (int m = 0; m < FM; m++) {
#pragma unroll
        for (int n = 0; n < FN; n++) {
            int col = n0 + wn * WN + n * 16 + lr;
            float bv = bias[col];
#pragma unroll
            for (int r = 0; r < 4; r++) {
                int row = m0 + wm * WM + m * 16 + 4 * g + r;
                float v = acc[m][n][r] + bv;
                if (ACT) v = gelu_f(v);
                if (RES) v += res[(size_t)row * N + col];
                stv(&out[(size_t)row * N + col], v);
            }
        }
    }
}

// ---------------- flash MFMA attention ----------------
// block = (64 q rows, 1 head); 4 waves, wave owns 16 q rows.
// qkv fp16 [1024][3072] (q|k|v); vT fp16 [1024 d][1024 key].
// K/V staged via global_load_lds (linear dest, source-side slot swizzle);
// P via per-wave LDS [q][key] slot-swizzled; fragment reads = ds_read_b128.
__global__ __launch_bounds__(256) void attn_mfma(
    const u16* __restrict__ qkv, const u16* __restrict__ vT,
    const float* __restrict__ mask, u16* __restrict__ y) {
    int h = blockIdx.y;
    int q0 = blockIdx.x * 64;
    int tid = threadIdx.x;
    int w = tid >> 6, l = tid & 63;
    int lr = l & 15, g = l >> 4;

    __shared__ u16 Ks[64 * 64];      // [key][d]
    __shared__ u16 Vs[64 * 64];      // [d][key]
    __shared__ u16 Ps[4 * 16 * 64];  // per-wave P: [q][key], slot-XOR swizzled
    __shared__ float maskb[1024];

    for (int i = tid; i < 1024; i += 256) maskb[i] = -1e9f * (1.f - mask[i]);

    f16x8 qf[2];
#pragma unroll
    for (int kf = 0; kf < 2; kf++)
        qf[kf] = *(const f16x8*)(qkv + (size_t)(q0 + w * 16 + lr) * 3072 + h * 64 + kf * 32 + g * 8);

    f32x4 o[4] = {};
    float mrow[4], lrow[4];
#pragma unroll
    for (int r = 0; r < 4; r++) { mrow[r] = -1e30f; lrow[r] = 0.f; }

    u16* Psw = Ps + w * 1024;

    for (int kc = 0; kc < 16; kc++) {
        __syncthreads();
#pragma unroll
        for (int i = 0; i < 2; i++) {
            int chunk = i * 256 + tid;
            int row = chunk >> 3, s = chunk & 7, sg = s ^ (row & 7);
            gl_lds16(qkv + (size_t)(kc * 64 + row) * 3072 + 1024 + h * 64 + sg * 8, Ks + chunk * 8);
            gl_lds16(vT + (size_t)(h * 64 + row) * 1024 + kc * 64 + sg * 8, Vs + chunk * 8);
        }
        __syncthreads();

        // S = Q @ K^T
        f32x4 s[4] = {};
#pragma unroll
        for (int n = 0; n < 4; n++)
#pragma unroll
            for (int kf = 0; kf < 2; kf++) {
                int row = n * 16 + lr;
                f16x8 kfrag = *(const f16x8*)(Ks + row * 64 + (((kf * 4 + g) ^ (row & 7)) * 8));
                s[n] = __builtin_amdgcn_mfma_f32_16x16x32_f16(qf[kf], kfrag, s[n], 0, 0, 0);
            }

        // online softmax (per r: row 4g+r; reduce over 4 n-frags + 16 lanes)
        float scl[4], mnew[4], psum[4];
#pragma unroll
        for (int r = 0; r < 4; r++) {
            float mx = -1e30f;
#pragma unroll
            for (int n = 0; n < 4; n++) {
                float sv = s[n][r] * 0.125f + maskb[kc * 64 + n * 16 + lr];
                s[n][r] = sv;
                mx = fmaxf(mx, sv);
            }
            mx = fmaxf(mx, __shfl_xor(mx, 1));
            mx = fmaxf(mx, __shfl_xor(mx, 2));
            mx = fmaxf(mx, __shfl_xor(mx, 4));
            mx = fmaxf(mx, __shfl_xor(mx, 8));
            mnew[r] = fmaxf(mrow[r], mx);
            scl[r] = __expf(mrow[r] - mnew[r]);
            mrow[r] = mnew[r];
            psum[r] = 0.f;
        }
        // P = exp(S - m); write P to per-wave LDS [q][key] (slot-swizzled)
#pragma unroll
        for (int n = 0; n < 4; n++) {
            float p0 = __expf(s[n][0] - mnew[0]);
            float p1 = __expf(s[n][1] - mnew[1]);
            float p2 = __expf(s[n][2] - mnew[2]);
            float p3 = __expf(s[n][3] - mnew[3]);
            psum[0] += p0; psum[1] += p1; psum[2] += p2; psum[3] += p3;
            int col = n * 16 + lr, cs = col >> 3, cl = col & 7;
            int r0 = 4 * g;
            Psw[(r0 + 0) * 64 + ((cs ^ ((r0 + 0) & 7)) * 8) + cl] = f2h(p0);
            Psw[(r0 + 1) * 64 + ((cs ^ ((r0 + 1) & 7)) * 8) + cl] = f2h(p1);
            Psw[(r0 + 2) * 64 + ((cs ^ ((r0 + 2) & 7)) * 8) + cl] = f2h(p2);
            Psw[(r0 + 3) * 64 + ((cs ^ ((r0 + 3) & 7)) * 8) + cl] = f2h(p3);
        }
#pragma unroll
        for (int r = 0; r < 4; r++) {
            float ps_ = psum[r];
            ps_ += __shfl_xor(ps_, 1);
            ps_ += __shfl_xor(ps_, 2);
            ps_ += __shfl_xor(ps_, 4);
            ps_ += __shfl_xor(ps_, 8);
            lrow[r] = lrow[r] * scl[r] + ps_;
#pragma unroll
            for (int dn = 0; dn < 4; dn++) o[dn][r] *= scl[r];
        }

        // PV: A = P (row=q=lr), B = V (row=d). Same-wave LDS RAW is in-order.
        f16x8 pa[2];
#pragma unroll
        for (int kf = 0; kf < 2; kf++)
            pa[kf] = *(const f16x8*)(Psw + lr * 64 + (((kf * 4 + g) ^ (lr & 7)) * 8));
#pragma unroll
        for (int dn = 0; dn < 4; dn++) {
#pragma unroll
            for (int kf = 0; kf < 2; kf++) {
                int row = dn * 16 + lr;
                f16x8 vb = *(const f16x8*)(Vs + row * 64 + (((kf * 4 + g) ^ (row & 7)) * 8));
                o[dn] = __builtin_amdgcn_mfma_f32_16x16x32_f16(pa[kf], vb, o[dn], 0, 0, 0);
            }
        }
    }

    float inv[4];
#pragma unroll
    for (int r = 0; r < 4; r++) inv[r] = 1.f / lrow[r];
#pragma unroll
    for (int dn = 0; dn < 4; dn++)
#pragma unroll
        for (int r = 0; r < 4; r++) {
            int row = q0 + w * 16 + 4 * g + r;
            int col = h * 64 + dn * 16 + lr;
            y[(size_t)row * 1024 + col] = f2h(o[dn][r] * inv[r]);
        }
}

// ---------------- launch ----------------
extern "C" void kernel_launch(void* const* d_in, const int* in_sizes, int n_in,
                              void* d_out, int out_size, void* d_ws, size_t ws_size,
                              hipStream_t stream) {
    const float* inputs_embeds = (const float*)d_in[0];
    const float* attn_mask     = (const float*)d_in[1];
    const float* ln1_g = (const float*)d_in[2];
    const float* ln1_b = (const float*)d_in[3];
    const float* Wqkv  = (const float*)d_in[4];
    const float* bqkv  = (const float*)d_in[5];
    const float* Wo    = (const float*)d_in[6];
    const float* bo    = (const float*)d_in[7];
    const float* ln2_g = (const float*)d_in[8];
    const float* ln2_b = (const float*)d_in[9];
    const float* Wfc   = (const float*)d_in[10];
    const float* bfc   = (const float*)d_in[11];
    const float* Wmp   = (const float*)d_in[12];
    const float* bmp   = (const float*)d_in[13];
    const float* lnf_g = (const float*)d_in[14];
    const float* lnf_b = (const float*)d_in[15];
    float* out = (float*)d_out;

    char* ws = (char*)d_ws;
    float* x   = (float*)ws;                              // 4 MB fp32 residual
    u16* hbuf  = (u16*)(ws + (4u << 20));                 // 2 MB fp16 (ln out / attn y)
    u16* qkvb  = (u16*)(ws + (6u << 20));                 // 8 MB region (qkv 6MB | fc 8MB)
    u16* fcb   = qkvb;
    u16* ybuf  = hbuf;
    u16* wqT   = (u16*)(ws + (14u << 20));                // 6 MB  [3072][1024]
    u16* woT   = (u16*)(ws + (20u << 20));                // 2 MB  [1024][1024]
    u16* wfT   = (u16*)(ws + (22u << 20));                // 8 MB  [4096][1024]
    u16* wmT   = (u16*)(ws + (30u << 20));                // 8 MB  [1024][4096]
    u16* vTb   = (u16*)(ws + (38u << 20));                // 2 MB  [1024][1024] -> 40 MB total

    hipMemcpyAsync(x, inputs_embeds, (size_t)(1 << 20) * sizeof(float),
                   hipMemcpyDeviceToDevice, stream);

    for (int l = 0; l < 12; l++) {
        tr_cvt<<<dim3(48, 16), 256, 0, stream>>>(Wqkv + (size_t)l * 1024 * 3072, wqT, 1024, 3072);
        tr_cvt<<<dim3(16, 16), 256, 0, stream>>>(Wo + (size_t)l * 1024 * 1024, woT, 1024, 1024);
        tr_cvt<<<dim3(64, 16), 256, 0, stream>>>(Wfc + (size_t)l * 1024 * 4096, wfT, 1024, 4096);
        tr_cvt<<<dim3(16, 64), 256, 0, stream>>>(Wmp + (size_t)l * 4096 * 1024, wmT, 4096, 1024);

        ln_kernel<u16><<<1024, 256, 0, stream>>>(x, ln1_g + l * 1024, ln1_b + l * 1024, hbuf);
        // QKV: 1024x3072, 64x128 tiles -> 16x24 = 384 blocks
        gemm_f16<64, 128, 0, 0, u16><<<dim3(24, 16), 256, 0, stream>>>(
            hbuf, wqT, bqkv + (size_t)l * 3072, nullptr, qkvb, 1024, 3072, 1024);
        tr16<<<dim3(16, 16), 256, 0, stream>>>(qkvb + 2048, vTb);
        attn_mfma<<<dim3(16, 16), 256, 0, stream>>>(qkvb, vTb, attn_mask, ybuf);
        // proj: 1024x1024, 64x64 tiles -> 256 blocks
        gemm_f16<64, 64, 0, 1, float><<<dim3(16, 16), 256, 0, stream>>>(
            ybuf, woT, bo + (size_t)l * 1024, x, x, 1024, 1024, 1024);
        ln_kernel<u16><<<1024, 256, 0, stream>>>(x, ln2_g + l * 1024, ln2_b + l * 1024, hbuf);
        // FC: 1024x4096, 128x128 tiles -> 8x32 = 256 blocks
        gemm_f16<128, 128, 1, 0, u16><<<dim3(32, 8), 256, 0, stream>>>(
            hbuf, wfT, bfc + (size_t)l * 4096, nullptr, fcb, 1024, 4096, 1024);
        // MP: 1024x1024 (K=4096), 64x64 tiles -> 256 blocks
        gemm_f16<64, 64, 0, 1, float><<<dim3(16, 16), 256, 0, stream>>>(
            fcb, wmT, bmp + (size_t)l * 1024, x, x, 1024, 1024, 4096);
    }
    ln_kernel<float><<<1024, 256, 0, stream>>>(x, lnf_g, lnf_b, out);
}

// Round 6
// 1682.665 us; speedup vs baseline: 10.6068x; 1.1722x over previous
//
#include <hip/hip_runtime.h>
#include <hip/hip_bf16.h>
#include <math.h>

#define LN_EPS 1e-5f

typedef unsigned short u16;
typedef __attribute__((ext_vector_type(8))) _Float16 f16x8;
typedef __attribute__((ext_vector_type(4))) float f32x4;

__device__ __forceinline__ u16 f2h(float x) {
    _Float16 h = (_Float16)x;
    return __builtin_bit_cast(u16, h);
}
__device__ __forceinline__ void stv(float* p, float v) { *p = v; }
__device__ __forceinline__ void stv(u16* p, float v) { *p = f2h(v); }

__device__ __forceinline__ float gelu_f(float x) {
    const float kA = 0.7978845608028654f;  // sqrt(2/pi)
    return 0.5f * x * (1.f + tanhf(kA * (x + 0.044715f * x * x * x)));
}

// async global->LDS, 16B per lane; LDS dest = wave-uniform base + lane*16
__device__ __forceinline__ void gl_lds16(const u16* g, u16* l) {
    __builtin_amdgcn_global_load_lds(
        (const __attribute__((address_space(1))) unsigned int*)g,
        (__attribute__((address_space(3))) unsigned int*)l, 16, 0, 0);
}

// ---------------- LayerNorm: one block per row, templated output ----------------
template <typename OT>
__global__ __launch_bounds__(256) void ln_kernel(const float* __restrict__ x,
                                                 const float* __restrict__ gam,
                                                 const float* __restrict__ bet,
                                                 OT* __restrict__ out) {
    int row = blockIdx.x;
    const float* xr = x + (size_t)row * 1024;
    float v[4];
    float s = 0.f, ss = 0.f;
#pragma unroll
    for (int i = 0; i < 4; i++) {
        float t = xr[threadIdx.x + i * 256];
        v[i] = t; s += t; ss += t * t;
    }
    __shared__ float r1[256], r2[256];
    r1[threadIdx.x] = s; r2[threadIdx.x] = ss;
    __syncthreads();
    for (int off = 128; off > 0; off >>= 1) {
        if (threadIdx.x < off) {
            r1[threadIdx.x] += r1[threadIdx.x + off];
            r2[threadIdx.x] += r2[threadIdx.x + off];
        }
        __syncthreads();
    }
    float mu = r1[0] * (1.f / 1024.f);
    float var = r2[0] * (1.f / 1024.f) - mu * mu;
    float rstd = rsqrtf(var + LN_EPS);
#pragma unroll
    for (int i = 0; i < 4; i++) {
        int c = threadIdx.x + i * 256;
        stv(&out[(size_t)row * 1024 + c], (v[i] - mu) * rstd * gam[c] + bet[c]);
    }
}

// ------- unified weight convert: all 4 weights of one layer in one dispatch -------
// fp32 [K][N] -> fp16 [N][K], 64x64 tiles. Flat tile id decodes which weight.
__global__ __launch_bounds__(256) void tr_cvt_all(
    const float* __restrict__ Wqkv, const float* __restrict__ Wo,
    const float* __restrict__ Wfc, const float* __restrict__ Wmp,
    u16* __restrict__ wqT, u16* __restrict__ woT,
    u16* __restrict__ wfT, u16* __restrict__ wmT) {
    int id = blockIdx.x;
    const float* W; u16* Wt; int K, N, idx;
    if (id < 768)       { W = Wqkv; Wt = wqT; K = 1024; N = 3072; idx = id; }
    else if (id < 1024) { W = Wo;   Wt = woT; K = 1024; N = 1024; idx = id - 768; }
    else if (id < 2048) { W = Wfc;  Wt = wfT; K = 1024; N = 4096; idx = id - 1024; }
    else                { W = Wmp;  Wt = wmT; K = 4096; N = 1024; idx = id - 2048; }
    int ntn = N >> 6;
    int n0 = (idx % ntn) * 64, k0 = (idx / ntn) * 64;

    __shared__ float tile[64][65];
    int t = threadIdx.x;
    int r = t >> 4, c4 = (t & 15) * 4;
#pragma unroll
    for (int p = 0; p < 4; p++) {
        float4 v = *(const float4*)(W + (size_t)(k0 + p * 16 + r) * N + n0 + c4);
        tile[p * 16 + r][c4 + 0] = v.x;
        tile[p * 16 + r][c4 + 1] = v.y;
        tile[p * 16 + r][c4 + 2] = v.z;
        tile[p * 16 + r][c4 + 3] = v.w;
    }
    __syncthreads();
#pragma unroll
    for (int p = 0; p < 4; p++) {
        int n = p * 16 + r;
        ushort4 o;
        o.x = f2h(tile[c4 + 0][n]);
        o.y = f2h(tile[c4 + 1][n]);
        o.z = f2h(tile[c4 + 2][n]);
        o.w = f2h(tile[c4 + 3][n]);
        *(ushort4*)(Wt + (size_t)(n0 + n) * K + k0 + c4) = o;
    }
}

// ---------------- fp16 MFMA GEMM: out[M,N] = A[M,K] @ Bt[N,K]^T + bias ----------------
// BMxBN tile, BK k-step, 4 waves (2x2). global_load_lds staging, linear LDS dest,
// k-slot swizzle (slot ^ (row&7)) applied on the GLOBAL source address.
// WVT: additionally write transposed V (cols>=2048 of QKV output) to vT[d][key].
template <int BM, int BN, int BK, int ACT, int RES, int WVT, typename OT>
__global__ __launch_bounds__(256) void gemm_f16(
    const u16* __restrict__ A, const u16* __restrict__ Bt,
    const float* __restrict__ bias, const float* __restrict__ res,
    OT* __restrict__ out, u16* __restrict__ vTout, int M, int N, int K) {
    __shared__ u16 As[BM * BK];
    __shared__ u16 Bs[BN * BK];
    constexpr int WM = BM / 2, WN = BN / 2;
    constexpr int FM = WM / 16, FN = WN / 16;
    constexpr int NKF = BK / 32;
    constexpr int SLOTS = BK / 8;
    constexpr int ACH = BM * BK / 8 / 256;
    constexpr int BCH = BN * BK / 8 / 256;
    int tid = threadIdx.x;
    int w = tid >> 6, l = tid & 63;
    int wm = w >> 1, wn = w & 1;
    int lr = l & 15, g = l >> 4;
    int m0 = blockIdx.y * BM, n0 = blockIdx.x * BN;

    f32x4 acc[FM][FN] = {};

    for (int k0 = 0; k0 < K; k0 += BK) {
        __syncthreads();
#pragma unroll
        for (int i = 0; i < ACH; i++) {
            int chunk = i * 256 + tid;
            int row = chunk / SLOTS, s = chunk % SLOTS, sg = s ^ (row & 7);
            gl_lds16(A + (size_t)(m0 + row) * K + k0 + sg * 8, As + chunk * 8);
        }
#pragma unroll
        for (int i = 0; i < BCH; i++) {
            int chunk = i * 256 + tid;
            int row = chunk / SLOTS, s = chunk % SLOTS, sg = s ^ (row & 7);
            gl_lds16(Bt + (size_t)(n0 + row) * K + k0 + sg * 8, Bs + chunk * 8);
        }
        __syncthreads();

        f16x8 af[FM][NKF], bfrag[FN][NKF];
#pragma unroll
        for (int m = 0; m < FM; m++)
#pragma unroll
            for (int kf = 0; kf < NKF; kf++) {
                int row = wm * WM + m * 16 + lr;
                af[m][kf] = *(const f16x8*)(As + row * BK + (((kf * 4 + g) ^ (row & 7)) * 8));
            }
#pragma unroll
        for (int n = 0; n < FN; n++)
#pragma unroll
            for (int kf = 0; kf < NKF; kf++) {
                int row = wn * WN + n * 16 + lr;
                bfrag[n][kf] = *(const f16x8*)(Bs + row * BK + (((kf * 4 + g) ^ (row & 7)) * 8));
            }
#pragma unroll
        for (int kf = 0; kf < NKF; kf++)
#pragma unroll
            for (int m = 0; m < FM; m++)
#pragma unroll
                for (int n = 0; n < FN; n++)
                    acc[m][n] = __builtin_amdgcn_mfma_f32_16x16x32_f16(
                        af[m][kf], bfrag[n][kf], acc[m][n], 0, 0, 0);
    }

#pragma unroll
    for (int m = 0; m < FM; m++) {
#pragma unroll
        for (int n = 0; n < FN; n++) {
            int col = n0 + wn * WN + n * 16 + lr;
            int row0 = m0 + wm * WM + m * 16 + 4 * g;
            float bv = bias[col];
            u16 hv[4];
#pragma unroll
            for (int r = 0; r < 4; r++) {
                float v = acc[m][n][r] + bv;
                if (ACT) v = gelu_f(v);
                if (RES) v += res[(size_t)(row0 + r) * N + col];
                stv(&out[(size_t)(row0 + r) * N + col], v);
                hv[r] = f2h(v);
            }
            if (WVT && col >= 2048) {
                ushort4 pv; pv.x = hv[0]; pv.y = hv[1]; pv.z = hv[2]; pv.w = hv[3];
                *(ushort4*)(vTout + (size_t)(col - 2048) * 1024 + row0) = pv;
            }
        }
    }
}

// ---------------- flash MFMA attention, KVBLK=128 ----------------
// block = (64 q rows, 1 head); 4 waves, wave owns 16 q rows.
// qkv fp16 [1024][3072] (q|k|v); vT fp16 [1024 d][1024 key].
// K/V staged via global_load_lds (linear dest, source-side slot swizzle);
// P in per-wave LDS [q][128 keys] slot-swizzled; fragment reads = ds_read_b128.
__global__ __launch_bounds__(256) void attn_mfma(
    const u16* __restrict__ qkv, const u16* __restrict__ vT,
    const float* __restrict__ mask, u16* __restrict__ y) {
    int h = blockIdx.y;
    int q0 = blockIdx.x * 64;
    int tid = threadIdx.x;
    int w = tid >> 6, l = tid & 63;
    int lr = l & 15, g = l >> 4;

    __shared__ u16 Ks[128 * 64];      // [key][d], 8 slots/row
    __shared__ u16 Vs[64 * 128];      // [d][key], 16 slots/row
    __shared__ u16 Ps[4 * 16 * 128];  // per-wave P: [q][key], 16 slots/row
    __shared__ float maskb[1024];

    for (int i = tid; i < 1024; i += 256) maskb[i] = -1e9f * (1.f - mask[i]);

    f16x8 qf[2];
#pragma unroll
    for (int kf = 0; kf < 2; kf++)
        qf[kf] = *(const f16x8*)(qkv + (size_t)(q0 + w * 16 + lr) * 3072 + h * 64 + kf * 32 + g * 8);

    f32x4 o[4] = {};
    float mrow[4], lrow[4];
#pragma unroll
    for (int r = 0; r < 4; r++) { mrow[r] = -1e30f; lrow[r] = 0.f; }

    u16* Psw = Ps + w * 2048;

    for (int kc = 0; kc < 8; kc++) {
        __syncthreads();
#pragma unroll
        for (int i = 0; i < 4; i++) {
            int chunk = i * 256 + tid;
            // K: 128 rows x 8 slots
            int krow = chunk >> 3, ks = chunk & 7, ksg = ks ^ (krow & 7);
            gl_lds16(qkv + (size_t)(kc * 128 + krow) * 3072 + 1024 + h * 64 + ksg * 8,
                     Ks + chunk * 8);
            // V: 64 rows x 16 slots
            int vrow = chunk >> 4, vs = chunk & 15, vsg = vs ^ (vrow & 7);
            gl_lds16(vT + (size_t)(h * 64 + vrow) * 1024 + kc * 128 + vsg * 8,
                     Vs + chunk * 8);
        }
        __syncthreads();

        // S = Q @ K^T : 8 key-frags of 16
        f32x4 s[8] = {};
#pragma unroll
        for (int n = 0; n < 8; n++)
#pragma unroll
            for (int kf = 0; kf < 2; kf++) {
                int row = n * 16 + lr;
                f16x8 kfrag = *(const f16x8*)(Ks + row * 64 + (((kf * 4 + g) ^ (row & 7)) * 8));
                s[n] = __builtin_amdgcn_mfma_f32_16x16x32_f16(qf[kf], kfrag, s[n], 0, 0, 0);
            }

        // online softmax (per r: row 4g+r; reduce over 8 n-frags + 16 lanes)
        float scl[4], mnew[4], psum[4];
#pragma unroll
        for (int r = 0; r < 4; r++) {
            float mx = -1e30f;
#pragma unroll
            for (int n = 0; n < 8; n++) {
                float sv = s[n][r] * 0.125f + maskb[kc * 128 + n * 16 + lr];
                s[n][r] = sv;
                mx = fmaxf(mx, sv);
            }
            mx = fmaxf(mx, __shfl_xor(mx, 1));
            mx = fmaxf(mx, __shfl_xor(mx, 2));
            mx = fmaxf(mx, __shfl_xor(mx, 4));
            mx = fmaxf(mx, __shfl_xor(mx, 8));
            mnew[r] = fmaxf(mrow[r], mx);
            scl[r] = __expf(mrow[r] - mnew[r]);
            mrow[r] = mnew[r];
            psum[r] = 0.f;
        }
        // P = exp(S - m); write P to per-wave LDS [q][key] (slot-swizzled)
#pragma unroll
        for (int n = 0; n < 8; n++) {
            float p0 = __expf(s[n][0] - mnew[0]);
            float p1 = __expf(s[n][1] - mnew[1]);
            float p2 = __expf(s[n][2] - mnew[2]);
            float p3 = __expf(s[n][3] - mnew[3]);
            psum[0] += p0; psum[1] += p1; psum[2] += p2; psum[3] += p3;
            int col = n * 16 + lr, cs = col >> 3, cl = col & 7;
            int r0 = 4 * g;
            Psw[(r0 + 0) * 128 + ((cs ^ ((r0 + 0) & 7)) * 8) + cl] = f2h(p0);
            Psw[(r0 + 1) * 128 + ((cs ^ ((r0 + 1) & 7)) * 8) + cl] = f2h(p1);
            Psw[(r0 + 2) * 128 + ((cs ^ ((r0 + 2) & 7)) * 8) + cl] = f2h(p2);
            Psw[(r0 + 3) * 128 + ((cs ^ ((r0 + 3) & 7)) * 8) + cl] = f2h(p3);
        }
#pragma unroll
        for (int r = 0; r < 4; r++) {
            float ps_ = psum[r];
            ps_ += __shfl_xor(ps_, 1);
            ps_ += __shfl_xor(ps_, 2);
            ps_ += __shfl_xor(ps_, 4);
            ps_ += __shfl_xor(ps_, 8);
            lrow[r] = lrow[r] * scl[r] + ps_;
#pragma unroll
            for (int dn = 0; dn < 4; dn++) o[dn][r] *= scl[r];
        }

        // PV: A = P (row=q=lr), B = V (row=d). Same-wave LDS RAW is in-order.
        f16x8 pa[4];
#pragma unroll
        for (int kf = 0; kf < 4; kf++)
            pa[kf] = *(const f16x8*)(Psw + lr * 128 + (((kf * 4 + g) ^ (lr & 7)) * 8));
#pragma unroll
        for (int dn = 0; dn < 4; dn++) {
#pragma unroll
            for (int kf = 0; kf < 4; kf++) {
                int row = dn * 16 + lr;
                f16x8 vb = *(const f16x8*)(Vs + row * 128 + (((kf * 4 + g) ^ (row & 7)) * 8));
                o[dn] = __builtin_amdgcn_mfma_f32_16x16x32_f16(pa[kf], vb, o[dn], 0, 0, 0);
            }
        }
    }

    float inv[4];
#pragma unroll
    for (int r = 0; r < 4; r++) inv[r] = 1.f / lrow[r];
#pragma unroll
    for (int dn = 0; dn < 4; dn++)
#pragma unroll
        for (int r = 0; r < 4; r++) {
            int row = q0 + w * 16 + 4 * g + r;
            int col = h * 64 + dn * 16 + lr;
            y[(size_t)row * 1024 + col] = f2h(o[dn][r] * inv[r]);
        }
}

// ---------------- launch ----------------
extern "C" void kernel_launch(void* const* d_in, const int* in_sizes, int n_in,
                              void* d_out, int out_size, void* d_ws, size_t ws_size,
                              hipStream_t stream) {
    const float* inputs_embeds = (const float*)d_in[0];
    const float* attn_mask     = (const float*)d_in[1];
    const float* ln1_g = (const float*)d_in[2];
    const float* ln1_b = (const float*)d_in[3];
    const float* Wqkv  = (const float*)d_in[4];
    const float* bqkv  = (const float*)d_in[5];
    const float* Wo    = (const float*)d_in[6];
    const float* bo    = (const float*)d_in[7];
    const float* ln2_g = (const float*)d_in[8];
    const float* ln2_b = (const float*)d_in[9];
    const float* Wfc   = (const float*)d_in[10];
    const float* bfc   = (const float*)d_in[11];
    const float* Wmp   = (const float*)d_in[12];
    const float* bmp   = (const float*)d_in[13];
    const float* lnf_g = (const float*)d_in[14];
    const float* lnf_b = (const float*)d_in[15];
    float* out = (float*)d_out;

    char* ws = (char*)d_ws;
    float* x   = (float*)ws;                              // 4 MB fp32 residual
    u16* hbuf  = (u16*)(ws + (4u << 20));                 // 2 MB fp16 (ln out / attn y)
    u16* qkvb  = (u16*)(ws + (6u << 20));                 // 8 MB region (qkv 6MB | fc 8MB)
    u16* fcb   = qkvb;
    u16* ybuf  = hbuf;
    u16* wqT   = (u16*)(ws + (14u << 20));                // 6 MB  [3072][1024]
    u16* woT   = (u16*)(ws + (20u << 20));                // 2 MB  [1024][1024]
    u16* wfT   = (u16*)(ws + (22u << 20));                // 8 MB  [4096][1024]
    u16* wmT   = (u16*)(ws + (30u << 20));                // 8 MB  [1024][4096]
    u16* vTb   = (u16*)(ws + (38u << 20));                // 2 MB  [1024][1024] -> 40 MB total

    hipMemcpyAsync(x, inputs_embeds, (size_t)(1 << 20) * sizeof(float),
                   hipMemcpyDeviceToDevice, stream);

    for (int l = 0; l < 12; l++) {
        tr_cvt_all<<<3072, 256, 0, stream>>>(
            Wqkv + (size_t)l * 1024 * 3072, Wo + (size_t)l * 1024 * 1024,
            Wfc + (size_t)l * 1024 * 4096, Wmp + (size_t)l * 4096 * 1024,
            wqT, woT, wfT, wmT);

        ln_kernel<u16><<<1024, 256, 0, stream>>>(x, ln1_g + l * 1024, ln1_b + l * 1024, hbuf);
        // QKV: 1024x3072, 64x128 tiles -> 384 blocks; fused vT write
        gemm_f16<64, 128, 64, 0, 0, 1, u16><<<dim3(24, 16), 256, 0, stream>>>(
            hbuf, wqT, bqkv + (size_t)l * 3072, nullptr, qkvb, vTb, 1024, 3072, 1024);
        attn_mfma<<<dim3(16, 16), 256, 0, stream>>>(qkvb, vTb, attn_mask, ybuf);
        // proj: 1024x1024, 64x64 tiles, BK=128 -> 256 blocks
        gemm_f16<64, 64, 128, 0, 1, 0, float><<<dim3(16, 16), 256, 0, stream>>>(
            ybuf, woT, bo + (size_t)l * 1024, x, x, nullptr, 1024, 1024, 1024);
        ln_kernel<u16><<<1024, 256, 0, stream>>>(x, ln2_g + l * 1024, ln2_b + l * 1024, hbuf);
        // FC: 1024x4096, 128x128 tiles -> 256 blocks
        gemm_f16<128, 128, 64, 1, 0, 0, u16><<<dim3(32, 8), 256, 0, stream>>>(
            hbuf, wfT, bfc + (size_t)l * 4096, nullptr, fcb, nullptr, 1024, 4096, 1024);
        // MP: 1024x1024 (K=4096), 64x64 tiles, BK=128 -> 256 blocks
        gemm_f16<64, 64, 128, 0, 1, 0, float><<<dim3(16, 16), 256, 0, stream>>>(
            fcb, wmT, bmp + (size_t)l * 1024, x, x, nullptr, 1024, 1024, 4096);
    }
    ln_kernel<float><<<1024, 256, 0, stream>>>(x, lnf_g, lnf_b, out);
}

// Round 7
// 1597.570 us; speedup vs baseline: 11.1718x; 1.0533x over previous
//
#include <hip/hip_runtime.h>
#include <hip/hip_bf16.h>
#include <math.h>

#define LN_EPS 1e-5f

typedef unsigned short u16;
typedef __attribute__((ext_vector_type(8))) _Float16 f16x8;
typedef __attribute__((ext_vector_type(4))) float f32x4;

__device__ __forceinline__ u16 f2h(float x) {
    _Float16 h = (_Float16)x;
    return __builtin_bit_cast(u16, h);
}
__device__ __forceinline__ void stv(float* p, float v) { *p = v; }
__device__ __forceinline__ void stv(u16* p, float v) { *p = f2h(v); }

__device__ __forceinline__ float gelu_f(float x) {
    const float kA = 0.7978845608028654f;  // sqrt(2/pi)
    return 0.5f * x * (1.f + tanhf(kA * (x + 0.044715f * x * x * x)));
}

// async global->LDS, 16B per lane; LDS dest = wave-uniform base + lane*16
__device__ __forceinline__ void gl_lds16(const u16* g, u16* l) {
    __builtin_amdgcn_global_load_lds(
        (const __attribute__((address_space(1))) unsigned int*)g,
        (__attribute__((address_space(3))) unsigned int*)l, 16, 0, 0);
}
// counted vmem wait (T4): wait until <=N vector-memory ops outstanding
template <int N> __device__ __forceinline__ void s_vmcnt() {
    asm volatile("s_waitcnt vmcnt(%0)" :: "n"(N) : "memory");
}
__device__ __forceinline__ void s_lgkm0() {
    asm volatile("s_waitcnt lgkmcnt(0)" ::: "memory");
    __builtin_amdgcn_sched_barrier(0);
}
__device__ __forceinline__ void bar() { __builtin_amdgcn_s_barrier(); }
__device__ __forceinline__ void sfence() { __builtin_amdgcn_sched_barrier(0); }

// ---------------- LayerNorm: one block per row, templated output ----------------
template <typename OT>
__global__ __launch_bounds__(256) void ln_kernel(const float* __restrict__ x,
                                                 const float* __restrict__ gam,
                                                 const float* __restrict__ bet,
                                                 OT* __restrict__ out) {
    int row = blockIdx.x;
    const float* xr = x + (size_t)row * 1024;
    float v[4];
    float s = 0.f, ss = 0.f;
#pragma unroll
    for (int i = 0; i < 4; i++) {
        float t = xr[threadIdx.x + i * 256];
        v[i] = t; s += t; ss += t * t;
    }
    __shared__ float r1[256], r2[256];
    r1[threadIdx.x] = s; r2[threadIdx.x] = ss;
    __syncthreads();
    for (int off = 128; off > 0; off >>= 1) {
        if (threadIdx.x < off) {
            r1[threadIdx.x] += r1[threadIdx.x + off];
            r2[threadIdx.x] += r2[threadIdx.x + off];
        }
        __syncthreads();
    }
    float mu = r1[0] * (1.f / 1024.f);
    float var = r2[0] * (1.f / 1024.f) - mu * mu;
    float rstd = rsqrtf(var + LN_EPS);
#pragma unroll
    for (int i = 0; i < 4; i++) {
        int c = threadIdx.x + i * 256;
        stv(&out[(size_t)row * 1024 + c], (v[i] - mu) * rstd * gam[c] + bet[c]);
    }
}

// ------- unified weight convert: all 4 weights of one layer in one dispatch -------
__global__ __launch_bounds__(256) void tr_cvt_all(
    const float* __restrict__ Wqkv, const float* __restrict__ Wo,
    const float* __restrict__ Wfc, const float* __restrict__ Wmp,
    u16* __restrict__ wqT, u16* __restrict__ woT,
    u16* __restrict__ wfT, u16* __restrict__ wmT) {
    int id = blockIdx.x;
    const float* W; u16* Wt; int K, N, idx;
    if (id < 768)       { W = Wqkv; Wt = wqT; K = 1024; N = 3072; idx = id; }
    else if (id < 1024) { W = Wo;   Wt = woT; K = 1024; N = 1024; idx = id - 768; }
    else if (id < 2048) { W = Wfc;  Wt = wfT; K = 1024; N = 4096; idx = id - 1024; }
    else                { W = Wmp;  Wt = wmT; K = 4096; N = 1024; idx = id - 2048; }
    int ntn = N >> 6;
    int n0 = (idx % ntn) * 64, k0 = (idx / ntn) * 64;

    __shared__ float tile[64][65];
    int t = threadIdx.x;
    int r = t >> 4, c4 = (t & 15) * 4;
#pragma unroll
    for (int p = 0; p < 4; p++) {
        float4 v = *(const float4*)(W + (size_t)(k0 + p * 16 + r) * N + n0 + c4);
        tile[p * 16 + r][c4 + 0] = v.x;
        tile[p * 16 + r][c4 + 1] = v.y;
        tile[p * 16 + r][c4 + 2] = v.z;
        tile[p * 16 + r][c4 + 3] = v.w;
    }
    __syncthreads();
#pragma unroll
    for (int p = 0; p < 4; p++) {
        int n = p * 16 + r;
        ushort4 o;
        o.x = f2h(tile[c4 + 0][n]);
        o.y = f2h(tile[c4 + 1][n]);
        o.z = f2h(tile[c4 + 2][n]);
        o.w = f2h(tile[c4 + 3][n]);
        *(ushort4*)(Wt + (size_t)(n0 + n) * K + k0 + c4) = o;
    }
}

// ---------------- fp16 MFMA GEMM, 2-phase pipelined ----------------
// out[M,N] = A[M,K] @ Bt[N,K]^T + bias. BMxBN tile, BK k-step, 4 waves (2x2).
// Double-buffered LDS; stage tile t+1 via global_load_lds BEFORE computing
// tile t; counted s_waitcnt vmcnt(LPS) + raw s_barrier (no vmcnt(0) drain).
// k-slot swizzle (slot ^ (row&7)) applied on the GLOBAL source address.
template <int BM, int BN, int BK, int ACT, int RES, int WVT, typename OT>
__global__ __launch_bounds__(256) void gemm_f16(
    const u16* __restrict__ A, const u16* __restrict__ Bt,
    const float* __restrict__ bias, const float* __restrict__ res,
    OT* __restrict__ out, u16* __restrict__ vTout, int M, int N, int K) {
    __shared__ u16 As[2][BM * BK];
    __shared__ u16 Bs[2][BN * BK];
    constexpr int WM = BM / 2, WN = BN / 2;
    constexpr int FM = WM / 16, FN = WN / 16;
    constexpr int NKF = BK / 32;
    constexpr int SLOTS = BK / 8;
    constexpr int ACH = BM * BK / 8 / 256;
    constexpr int BCH = BN * BK / 8 / 256;
    constexpr int LPS = ACH + BCH;  // gl_lds16 per thread per stage
    int tid = threadIdx.x;
    int w = tid >> 6, l = tid & 63;
    int wm = w >> 1, wn = w & 1;
    int lr = l & 15, g = l >> 4;
    int m0 = blockIdx.y * BM, n0 = blockIdx.x * BN;

    f32x4 acc[FM][FN] = {};

    auto stage = [&](int buf, int k0) {
#pragma unroll
        for (int i = 0; i < ACH; i++) {
            int chunk = i * 256 + tid;
            int row = chunk / SLOTS, s = chunk % SLOTS, sg = s ^ (row & 7);
            gl_lds16(A + (size_t)(m0 + row) * K + k0 + sg * 8, &As[buf][chunk * 8]);
        }
#pragma unroll
        for (int i = 0; i < BCH; i++) {
            int chunk = i * 256 + tid;
            int row = chunk / SLOTS, s = chunk % SLOTS, sg = s ^ (row & 7);
            gl_lds16(Bt + (size_t)(n0 + row) * K + k0 + sg * 8, &Bs[buf][chunk * 8]);
        }
    };

    int NT = K / BK;
    stage(0, 0);
    int cur = 0;
    for (int t = 0; t < NT; t++) {
        if (t + 1 < NT) { stage(cur ^ 1, (t + 1) * BK); s_vmcnt<LPS>(); }
        else            { s_vmcnt<0>(); }
        bar();      // tile t staged by all waves
        sfence();

        const u16* Ab = &As[cur][0];
        const u16* Bb = &Bs[cur][0];
        f16x8 af[FM][NKF], bfrag[FN][NKF];
#pragma unroll
        for (int m = 0; m < FM; m++)
#pragma unroll
            for (int kf = 0; kf < NKF; kf++) {
                int row = wm * WM + m * 16 + lr;
                af[m][kf] = *(const f16x8*)(Ab + row * BK + (((kf * 4 + g) ^ (row & 7)) * 8));
            }
#pragma unroll
        for (int n = 0; n < FN; n++)
#pragma unroll
            for (int kf = 0; kf < NKF; kf++) {
                int row = wn * WN + n * 16 + lr;
                bfrag[n][kf] = *(const f16x8*)(Bb + row * BK + (((kf * 4 + g) ^ (row & 7)) * 8));
            }
#pragma unroll
        for (int kf = 0; kf < NKF; kf++)
#pragma unroll
            for (int m = 0; m < FM; m++)
#pragma unroll
                for (int n = 0; n < FN; n++)
                    acc[m][n] = __builtin_amdgcn_mfma_f32_16x16x32_f16(
                        af[m][kf], bfrag[n][kf], acc[m][n], 0, 0, 0);

        sfence();
        bar();      // all waves done reading buf[cur] before it is re-staged
        cur ^= 1;
    }

#pragma unroll
    for (int m = 0; m < FM; m++) {
#pragma unroll
        for (int n = 0; n < FN; n++) {
            int col = n0 + wn * WN + n * 16 + lr;
            int row0 = m0 + wm * WM + m * 16 + 4 * g;
            float bv = bias[col];
            u16 hv[4];
#pragma unroll
            for (int r = 0; r < 4; r++) {
                float v = acc[m][n][r] + bv;
                if (ACT) v = gelu_f(v);
                if (RES) v += res[(size_t)(row0 + r) * N + col];
                stv(&out[(size_t)(row0 + r) * N + col], v);
                hv[r] = f2h(v);
            }
            if (WVT && col >= 2048) {
                ushort4 pv; pv.x = hv[0]; pv.y = hv[1]; pv.z = hv[2]; pv.w = hv[3];
                *(ushort4*)(vTout + (size_t)(col - 2048) * 1024 + row0) = pv;
            }
        }
    }
}

// ---------------- flash MFMA attention, KVBLK=128, 2-phase pipelined ----------------
// block = (64 q rows, 1 head); 4 waves, wave owns 16 q rows.
// K/V double-buffered in LDS (staged via global_load_lds, source-side swizzle);
// P in per-wave LDS [q][128] slot-swizzled; all fragment reads = ds_read_b128.
__global__ __launch_bounds__(256) void attn_mfma(
    const u16* __restrict__ qkv, const u16* __restrict__ vT,
    const float* __restrict__ mask, u16* __restrict__ y) {
    int h = blockIdx.y;
    int q0 = blockIdx.x * 64;
    int tid = threadIdx.x;
    int w = tid >> 6, l = tid & 63;
    int lr = l & 15, g = l >> 4;

    __shared__ u16 Ks[2][128 * 64];   // [key][d], 8 slots/row
    __shared__ u16 Vs[2][64 * 128];   // [d][key], 16 slots/row
    __shared__ u16 Ps[4 * 16 * 128];  // per-wave P: [q][key], 16 slots/row
    __shared__ float maskb[1024];

    for (int i = tid; i < 1024; i += 256) maskb[i] = -1e9f * (1.f - mask[i]);
    s_lgkm0();  // own maskb writes landed before first barrier

    f16x8 qf[2];
#pragma unroll
    for (int kf = 0; kf < 2; kf++)
        qf[kf] = *(const f16x8*)(qkv + (size_t)(q0 + w * 16 + lr) * 3072 + h * 64 + kf * 32 + g * 8);

    f32x4 o[4] = {};
    float mrow[4], lrow[4];
#pragma unroll
    for (int r = 0; r < 4; r++) { mrow[r] = -1e30f; lrow[r] = 0.f; }

    u16* Psw = Ps + w * 2048;

    auto stage = [&](int buf, int kc) {
#pragma unroll
        for (int i = 0; i < 4; i++) {
            int chunk = i * 256 + tid;
            int krow = chunk >> 3, ks = chunk & 7, ksg = ks ^ (krow & 7);
            gl_lds16(qkv + (size_t)(kc * 128 + krow) * 3072 + 1024 + h * 64 + ksg * 8,
                     &Ks[buf][chunk * 8]);
            int vrow = chunk >> 4, vs = chunk & 15, vsg = vs ^ (vrow & 7);
            gl_lds16(vT + (size_t)(h * 64 + vrow) * 1024 + kc * 128 + vsg * 8,
                     &Vs[buf][chunk * 8]);
        }
    };

    stage(0, 0);
    int cur = 0;
    for (int kc = 0; kc < 8; kc++) {
        if (kc + 1 < 8) { stage(cur ^ 1, kc + 1); s_vmcnt<8>(); }
        else            { s_vmcnt<0>(); }
        bar();
        sfence();
        const u16* Kb = &Ks[cur][0];
        const u16* Vb = &Vs[cur][0];

        // S = Q @ K^T : 8 key-frags of 16
        f32x4 s[8] = {};
        __builtin_amdgcn_s_setprio(1);
#pragma unroll
        for (int n = 0; n < 8; n++)
#pragma unroll
            for (int kf = 0; kf < 2; kf++) {
                int row = n * 16 + lr;
                f16x8 kfrag = *(const f16x8*)(Kb + row * 64 + (((kf * 4 + g) ^ (row & 7)) * 8));
                s[n] = __builtin_amdgcn_mfma_f32_16x16x32_f16(qf[kf], kfrag, s[n], 0, 0, 0);
            }
        __builtin_amdgcn_s_setprio(0);

        float mcol[8];
#pragma unroll
        for (int n = 0; n < 8; n++) mcol[n] = maskb[kc * 128 + n * 16 + lr];

        // online softmax (per r: row 4g+r; reduce over 8 n-frags + 16 lanes)
        float scl[4], mnew[4], psum[4];
#pragma unroll
        for (int r = 0; r < 4; r++) {
            float mx = -1e30f;
#pragma unroll
            for (int n = 0; n < 8; n++) {
                float sv = s[n][r] * 0.125f + mcol[n];
                s[n][r] = sv;
                mx = fmaxf(mx, sv);
            }
            mx = fmaxf(mx, __shfl_xor(mx, 1));
            mx = fmaxf(mx, __shfl_xor(mx, 2));
            mx = fmaxf(mx, __shfl_xor(mx, 4));
            mx = fmaxf(mx, __shfl_xor(mx, 8));
            mnew[r] = fmaxf(mrow[r], mx);
            scl[r] = __expf(mrow[r] - mnew[r]);
            mrow[r] = mnew[r];
            psum[r] = 0.f;
        }
        // P = exp(S - m); write P to per-wave LDS [q][key] (slot-swizzled)
#pragma unroll
        for (int n = 0; n < 8; n++) {
            float p0 = __expf(s[n][0] - mnew[0]);
            float p1 = __expf(s[n][1] - mnew[1]);
            float p2 = __expf(s[n][2] - mnew[2]);
            float p3 = __expf(s[n][3] - mnew[3]);
            psum[0] += p0; psum[1] += p1; psum[2] += p2; psum[3] += p3;
            int col = n * 16 + lr, cs = col >> 3, cl = col & 7;
            int r0 = 4 * g;
            Psw[(r0 + 0) * 128 + ((cs ^ ((r0 + 0) & 7)) * 8) + cl] = f2h(p0);
            Psw[(r0 + 1) * 128 + ((cs ^ ((r0 + 1) & 7)) * 8) + cl] = f2h(p1);
            Psw[(r0 + 2) * 128 + ((cs ^ ((r0 + 2) & 7)) * 8) + cl] = f2h(p2);
            Psw[(r0 + 3) * 128 + ((cs ^ ((r0 + 3) & 7)) * 8) + cl] = f2h(p3);
        }
#pragma unroll
        for (int r = 0; r < 4; r++) {
            float ps_ = psum[r];
            ps_ += __shfl_xor(ps_, 1);
            ps_ += __shfl_xor(ps_, 2);
            ps_ += __shfl_xor(ps_, 4);
            ps_ += __shfl_xor(ps_, 8);
            lrow[r] = lrow[r] * scl[r] + ps_;
#pragma unroll
            for (int dn = 0; dn < 4; dn++) o[dn][r] *= scl[r];
        }

        // PV: A = P (row=q=lr), B = V (row=d). Same-wave LDS RAW is in-order.
        f16x8 pa[4];
#pragma unroll
        for (int kf = 0; kf < 4; kf++)
            pa[kf] = *(const f16x8*)(Psw + lr * 128 + (((kf * 4 + g) ^ (lr & 7)) * 8));
        __builtin_amdgcn_s_setprio(1);
#pragma unroll
        for (int dn = 0; dn < 4; dn++) {
#pragma unroll
            for (int kf = 0; kf < 4; kf++) {
                int row = dn * 16 + lr;
                f16x8 vb = *(const f16x8*)(Vb + row * 128 + (((kf * 4 + g) ^ (row & 7)) * 8));
                o[dn] = __builtin_amdgcn_mfma_f32_16x16x32_f16(pa[kf], vb, o[dn], 0, 0, 0);
            }
        }
        __builtin_amdgcn_s_setprio(0);

        sfence();
        bar();      // all waves done reading buf[cur] before it is re-staged
        cur ^= 1;
    }

    float inv[4];
#pragma unroll
    for (int r = 0; r < 4; r++) inv[r] = 1.f / lrow[r];
#pragma unroll
    for (int dn = 0; dn < 4; dn++)
#pragma unroll
        for (int r = 0; r < 4; r++) {
            int row = q0 + w * 16 + 4 * g + r;
            int col = h * 64 + dn * 16 + lr;
            y[(size_t)row * 1024 + col] = f2h(o[dn][r] * inv[r]);
        }
}

// ---------------- launch ----------------
extern "C" void kernel_launch(void* const* d_in, const int* in_sizes, int n_in,
                              void* d_out, int out_size, void* d_ws, size_t ws_size,
                              hipStream_t stream) {
    const float* inputs_embeds = (const float*)d_in[0];
    const float* attn_mask     = (const float*)d_in[1];
    const float* ln1_g = (const float*)d_in[2];
    const float* ln1_b = (const float*)d_in[3];
    const float* Wqkv  = (const float*)d_in[4];
    const float* bqkv  = (const float*)d_in[5];
    const float* Wo    = (const float*)d_in[6];
    const float* bo    = (const float*)d_in[7];
    const float* ln2_g = (const float*)d_in[8];
    const float* ln2_b = (const float*)d_in[9];
    const float* Wfc   = (const float*)d_in[10];
    const float* bfc   = (const float*)d_in[11];
    const float* Wmp   = (const float*)d_in[12];
    const float* bmp   = (const float*)d_in[13];
    const float* lnf_g = (const float*)d_in[14];
    const float* lnf_b = (const float*)d_in[15];
    float* out = (float*)d_out;

    char* ws = (char*)d_ws;
    float* x   = (float*)ws;                              // 4 MB fp32 residual
    u16* hbuf  = (u16*)(ws + (4u << 20));                 // 2 MB fp16 (ln out / attn y)
    u16* qkvb  = (u16*)(ws + (6u << 20));                 // 8 MB region (qkv 6MB | fc 8MB)
    u16* fcb   = qkvb;
    u16* ybuf  = hbuf;
    u16* wqT   = (u16*)(ws + (14u << 20));                // 6 MB  [3072][1024]
    u16* woT   = (u16*)(ws + (20u << 20));                // 2 MB  [1024][1024]
    u16* wfT   = (u16*)(ws + (22u << 20));                // 8 MB  [4096][1024]
    u16* wmT   = (u16*)(ws + (30u << 20));                // 8 MB  [1024][4096]
    u16* vTb   = (u16*)(ws + (38u << 20));                // 2 MB  [1024][1024] -> 40 MB total

    hipMemcpyAsync(x, inputs_embeds, (size_t)(1 << 20) * sizeof(float),
                   hipMemcpyDeviceToDevice, stream);

    for (int l = 0; l < 12; l++) {
        tr_cvt_all<<<3072, 256, 0, stream>>>(
            Wqkv + (size_t)l * 1024 * 3072, Wo + (size_t)l * 1024 * 1024,
            Wfc + (size_t)l * 1024 * 4096, Wmp + (size_t)l * 4096 * 1024,
            wqT, woT, wfT, wmT);

        ln_kernel<u16><<<1024, 256, 0, stream>>>(x, ln1_g + l * 1024, ln1_b + l * 1024, hbuf);
        // QKV: 1024x3072, 64x128 tiles -> 384 blocks; fused vT write
        gemm_f16<64, 128, 64, 0, 0, 1, u16><<<dim3(24, 16), 256, 0, stream>>>(
            hbuf, wqT, bqkv + (size_t)l * 3072, nullptr, qkvb, vTb, 1024, 3072, 1024);
        attn_mfma<<<dim3(16, 16), 256, 0, stream>>>(qkvb, vTb, attn_mask, ybuf);
        // proj: 1024x1024, 64x64 tiles, BK=128 -> 256 blocks
        gemm_f16<64, 64, 128, 0, 1, 0, float><<<dim3(16, 16), 256, 0, stream>>>(
            ybuf, woT, bo + (size_t)l * 1024, x, x, nullptr, 1024, 1024, 1024);
        ln_kernel<u16><<<1024, 256, 0, stream>>>(x, ln2_g + l * 1024, ln2_b + l * 1024, hbuf);
        // FC: 1024x4096, 128x128 tiles -> 256 blocks
        gemm_f16<128, 128, 64, 1, 0, 0, u16><<<dim3(32, 8), 256, 0, stream>>>(
            hbuf, wfT, bfc + (size_t)l * 4096, nullptr, fcb, nullptr, 1024, 4096, 1024);
        // MP: 1024x1024 (K=4096), 64x64 tiles, BK=128 -> 256 blocks
        gemm_f16<64, 64, 128, 0, 1, 0, float><<<dim3(16, 16), 256, 0, stream>>>(
            fcb, wmT, bmp + (size_t)l * 1024, x, x, nullptr, 1024, 1024, 4096);
    }
    ln_kernel<float><<<1024, 256, 0, stream>>>(x, lnf_g, lnf_b, out);
}